// Round 6
// baseline (259.538 us; speedup 1.0000x reference)
//
#include <hip/hip_runtime.h>

constexpr int F = 64;

typedef float vf4 __attribute__((ext_vector_type(4)));
typedef int   vi2 __attribute__((ext_vector_type(2)));

// ---------------- zero scratch ----------------
__global__ void zero_kernel(int4* __restrict__ p, int n4) {
    int i = blockIdx.x * blockDim.x + threadIdx.x;
    if (i < n4) p[i] = make_int4(0, 0, 0, 0);
}

// ---------------- CSR build ----------------
__global__ void count_kernel(const int* __restrict__ idx,
                             int* __restrict__ counts, int M) {
    int e = blockIdx.x * blockDim.x + threadIdx.x;
    if (e < M) atomicAdd(&counts[idx[e]], 1);
}

// per-block exclusive scan of 256 counts; block total -> partials[blockIdx]
__global__ void scanA_kernel(const int* __restrict__ counts,
                             int* __restrict__ local_excl,
                             int* __restrict__ partials, int N) {
    __shared__ int wsum[4];
    int i = blockIdx.x * 256 + threadIdx.x;
    int lane = threadIdx.x & 63, wid = threadIdx.x >> 6;
    int v = (i < N) ? counts[i] : 0;
    int incl = v;
    #pragma unroll
    for (int off = 1; off < 64; off <<= 1) {
        int n = __shfl_up(incl, off);
        if (lane >= off) incl += n;
    }
    if (lane == 63) wsum[wid] = incl;
    __syncthreads();
    if (threadIdx.x == 0) {
        int s = 0;
        #pragma unroll
        for (int w = 0; w < 4; ++w) { int t = wsum[w]; wsum[w] = s; s += t; }
        partials[blockIdx.x] = s;
    }
    __syncthreads();
    if (i < N) local_excl[i] = incl - v + wsum[wid];
}

// single-wave exclusive scan of block partials
__global__ void scanB_kernel(int* __restrict__ partials, int nb) {
    int lane = threadIdx.x;  // 64 threads
    int carry = 0;
    for (int base = 0; base < nb; base += 64) {
        int i = base + lane;
        int v = (i < nb) ? partials[i] : 0;
        int incl = v;
        #pragma unroll
        for (int off = 1; off < 64; off <<= 1) {
            int n = __shfl_up(incl, off);
            if (lane >= off) incl += n;
        }
        if (i < nb) partials[i] = incl - v + carry;
        carry += __shfl(incl, 63);
    }
}

// fused permutation: pe[pos] = {edge_id, bits(exp(att))} — one 8B scattered store
__global__ void perm_kernel(const int* __restrict__ idx,
                            const float* __restrict__ att,
                            const int* __restrict__ local_excl,
                            const int* __restrict__ partials,
                            int* __restrict__ fill,
                            vi2* __restrict__ pe, int M) {
    int e = blockIdx.x * blockDim.x + threadIdx.x;
    if (e >= M) return;
    int node = idx[e];
    int pos = local_excl[node] + partials[node >> 8] + atomicAdd(&fill[node], 1);
    vi2 w; w.x = e; w.y = __float_as_int(expf(att[e]));
    pe[pos] = w;
}

// one wave per node. lane = (edge-slot lane>>4, feature-quad lane&15):
// each float4 wave-load covers 4 edge rows (1KB/instruction).
// Edge loads are CACHEABLE (let 256MB L3 serve ~60% of the random rows);
// pe metadata is single-touch -> nontemporal.
__global__ void gather_kernel(const vf4* __restrict__ edges4,
                              const vi2* __restrict__ pe,
                              const int* __restrict__ local_excl,
                              const int* __restrict__ partials,
                              const int* __restrict__ counts,
                              float* __restrict__ out, int N) {
    int node = blockIdx.x * (blockDim.x >> 6) + (threadIdx.x >> 6);
    int lane = threadIdx.x & 63;
    if (node >= N) return;
    int base = local_excl[node] + partials[node >> 8];
    int deg  = counts[node];
    int grp = lane >> 4;   // which of 4 rows this lane helps load
    int q   = lane & 15;   // feature quad
    vf4 acc = (vf4)(0.f);
    float s = 0.f;
    for (int c = 0; c < deg; c += 64) {
        int len = min(64, deg - c);
        int e = 0; float a = 0.f;
        if (lane < len) {
            vi2 v = __builtin_nontemporal_load(&pe[base + c + lane]);
            e = v.x; a = __int_as_float(v.y);
        }
        for (int t = 0; t < len; t += 16) {
            #pragma unroll
            for (int k = 0; k < 4; ++k) {
                int jj = t + k * 4 + grp;
                int ej   = __shfl(e, jj);
                float aj = __shfl(a, jj);
                if (jj >= len) aj = 0.f;
                vf4 v = edges4[(size_t)ej * 16 + q];
                acc += aj * v;
                s += aj;
            }
        }
    }
    // combine the 4 lane-groups (xor 16, 32)
    #pragma unroll
    for (int off = 16; off < 64; off <<= 1) {
        acc.x += __shfl_xor(acc.x, off);
        acc.y += __shfl_xor(acc.y, off);
        acc.z += __shfl_xor(acc.z, off);
        acc.w += __shfl_xor(acc.w, off);
        s     += __shfl_xor(s, off);
    }
    if (lane < 16) {
        float inv = (deg > 0) ? 1.f / s : 0.f;
        vf4 o = acc * inv;
        ((vf4*)out)[(size_t)node * 16 + q] = o;
    }
}

// ---------------- round-1 scatter fallback (tiny ws) ----------------
__global__ void denom_kernel(const float* __restrict__ att,
                             const int* __restrict__ idx,
                             float* __restrict__ denom, int M) {
    int e = blockIdx.x * blockDim.x + threadIdx.x;
    if (e < M) atomicAdd(&denom[idx[e]], expf(att[e]));
}

__global__ void scatter_kernel(const float4* __restrict__ edges4,
                               const float* __restrict__ att,
                               const int* __restrict__ idx,
                               const float* __restrict__ denom,
                               float* __restrict__ out, int M) {
    long long tid = (long long)blockIdx.x * blockDim.x + threadIdx.x;
    int e = (int)(tid >> 4);
    if (e >= M) return;
    int q = (int)(tid & 15);
    int node = idx[e];
    float alpha = expf(att[e]) / denom[node];
    float4 v = edges4[(size_t)e * 16 + q];
    float* o = out + (size_t)node * F + q * 4;
    atomicAdd(o + 0, v.x * alpha);
    atomicAdd(o + 1, v.y * alpha);
    atomicAdd(o + 2, v.z * alpha);
    atomicAdd(o + 3, v.w * alpha);
}

extern "C" void kernel_launch(void* const* d_in, const int* in_sizes, int n_in,
                              void* d_out, int out_size, void* d_ws, size_t ws_size,
                              hipStream_t stream) {
    // inputs: 0=reference (unused, N*F), 1=edges (M*F), 2=attention (M), 3=edge_index (2*M)
    const float* edges = (const float*)d_in[1];
    const float* att   = (const float*)d_in[2];
    const int*   eidx  = (const int*)d_in[3];   // row 0 = receiver idx
    int M = in_sizes[2];
    int N = in_sizes[0] / F;
    float* out = (float*)d_out;

    int nb = (N + 255) / 256;
    int threads = 256;
    int blocksM = (M + threads - 1) / threads;

    // ws layout: [counts N][fill N][local_excl N][partials nb][pe 2M ints]
    size_t need = ((size_t)3 * N + nb + (size_t)2 * M) * sizeof(int);

    if (ws_size >= need) {
        int* counts     = (int*)d_ws;
        int* fill       = counts + N;
        int* local_excl = fill + N;
        int* partials   = local_excl + N;
        vi2* pe         = (vi2*)(partials + nb);

        int n4 = (2 * N + 3) / 4;   // zero counts+fill (contiguous)
        zero_kernel<<<(n4 + threads - 1) / threads, threads, 0, stream>>>((int4*)counts, n4);
        count_kernel<<<blocksM, threads, 0, stream>>>(eidx, counts, M);
        scanA_kernel<<<nb, 256, 0, stream>>>(counts, local_excl, partials, N);
        scanB_kernel<<<1, 64, 0, stream>>>(partials, nb);
        perm_kernel<<<blocksM, threads, 0, stream>>>(eidx, att, local_excl, partials,
                                                     fill, pe, M);
        int nodes_per_block = threads / 64;
        int blocksN = (N + nodes_per_block - 1) / nodes_per_block;
        gather_kernel<<<blocksN, threads, 0, stream>>>(
            (const vf4*)edges, pe, local_excl, partials, counts, out, N);
    } else {
        float* denom = (float*)d_ws;
        int nz = (N + 3) / 4;
        zero_kernel<<<(nz + threads - 1) / threads, threads, 0, stream>>>((int4*)denom, nz);
        int o4 = (out_size + 3) / 4;
        zero_kernel<<<(o4 + threads - 1) / threads, threads, 0, stream>>>((int4*)out, o4);
        denom_kernel<<<blocksM, threads, 0, stream>>>(att, eidx, denom, M);
        long long total = (long long)M * 16;
        long long blocks2 = (total + threads - 1) / threads;
        scatter_kernel<<<(int)blocks2, threads, 0, stream>>>(
            (const float4*)edges, att, eidx, denom, out, M);
    }
}

// Round 7
// 190.870 us; speedup vs baseline: 1.3598x; 1.3598x over previous
//
#include <hip/hip_runtime.h>

constexpr int F = 64;

typedef float vf4 __attribute__((ext_vector_type(4)));

// ---------------- zero scratch ----------------
__global__ void zero_kernel(int4* __restrict__ p, int n4) {
    int i = blockIdx.x * blockDim.x + threadIdx.x;
    if (i < n4) p[i] = make_int4(0, 0, 0, 0);
}

// ---------------- CSR build ----------------
// pass 1: count + record within-node position (removes pass-2 atomics)
__global__ void count_pos_kernel(const int* __restrict__ idx,
                                 int* __restrict__ counts,
                                 int* __restrict__ pos, int M) {
    int e = blockIdx.x * blockDim.x + threadIdx.x;
    if (e < M) pos[e] = atomicAdd(&counts[idx[e]], 1);
}

// per-block exclusive scan of 256 counts; block total -> partials[blockIdx]
__global__ void scanA_kernel(const int* __restrict__ counts,
                             int* __restrict__ local_excl,
                             int* __restrict__ partials, int N) {
    __shared__ int wsum[4];
    int i = blockIdx.x * 256 + threadIdx.x;
    int lane = threadIdx.x & 63, wid = threadIdx.x >> 6;
    int v = (i < N) ? counts[i] : 0;
    int incl = v;
    #pragma unroll
    for (int off = 1; off < 64; off <<= 1) {
        int n = __shfl_up(incl, off);
        if (lane >= off) incl += n;
    }
    if (lane == 63) wsum[wid] = incl;
    __syncthreads();
    if (threadIdx.x == 0) {
        int s = 0;
        #pragma unroll
        for (int w = 0; w < 4; ++w) { int t = wsum[w]; wsum[w] = s; s += t; }
        partials[blockIdx.x] = s;
    }
    __syncthreads();
    if (i < N) local_excl[i] = incl - v + wsum[wid];
}

// single-wave exclusive scan of block partials
__global__ void scanB_kernel(int* __restrict__ partials, int nb) {
    int lane = threadIdx.x;  // 64 threads
    int carry = 0;
    for (int base = 0; base < nb; base += 64) {
        int i = base + lane;
        int v = (i < nb) ? partials[i] : 0;
        int incl = v;
        #pragma unroll
        for (int off = 1; off < 64; off <<= 1) {
            int n = __shfl_up(incl, off);
            if (lane >= off) incl += n;
        }
        if (i < nb) partials[i] = incl - v + carry;
        carry += __shfl(incl, 63);
    }
}

// pass 2: atomic-free scatter of {edge_id, exp(att)} into CSR slots
__global__ void perm_kernel(const int* __restrict__ idx,
                            const float* __restrict__ att,
                            const int* __restrict__ pos,
                            const int* __restrict__ local_excl,
                            const int* __restrict__ partials,
                            int2* __restrict__ pe, int M) {
    int e = blockIdx.x * blockDim.x + threadIdx.x;
    if (e >= M) return;
    int node = idx[e];
    int slot = local_excl[node] + partials[node >> 8] + pos[e];
    pe[slot] = make_int2(e, __float_as_int(expf(att[e])));
}

// one wave per node. lane = (edge-slot lane>>4, feature-quad lane&15):
// each float4 wave-load covers 4 edge rows (1KB/instruction).
// Edges are single-touch random rows -> nontemporal; pe streams through cache.
__global__ void gather_kernel(const vf4* __restrict__ edges4,
                              const int2* __restrict__ pe,
                              const int* __restrict__ local_excl,
                              const int* __restrict__ partials,
                              const int* __restrict__ counts,
                              float* __restrict__ out, int N) {
    int node = blockIdx.x * (blockDim.x >> 6) + (threadIdx.x >> 6);
    int lane = threadIdx.x & 63;
    if (node >= N) return;
    int base = local_excl[node] + partials[node >> 8];
    int deg  = counts[node];
    int grp = lane >> 4;   // which row-slot within each 16-row chunk
    int q   = lane & 15;   // feature quad
    vf4 acc = (vf4)(0.f);
    float s = 0.f;
    for (int c = 0; c < deg; c += 64) {
        int len = min(64, deg - c);
        int e = 0; float a = 0.f;
        if (lane < len) {
            int2 v = pe[base + c + lane];
            e = v.x; a = __int_as_float(v.y);
        }
        for (int t = 0; t < len; t += 16) {
            #pragma unroll
            for (int k = 0; k < 4; ++k) {
                int jj = t + k * 4 + grp;
                int ej   = __shfl(e, jj);
                float aj = __shfl(a, jj);
                if (jj < len) {   // mask tail groups: no wasted row-0 loads
                    vf4 v = __builtin_nontemporal_load(&edges4[(size_t)ej * 16 + q]);
                    acc += aj * v;
                    s += aj;
                }
            }
        }
    }
    // combine the 4 lane-groups (xor 16, 32)
    #pragma unroll
    for (int off = 16; off < 64; off <<= 1) {
        acc.x += __shfl_xor(acc.x, off);
        acc.y += __shfl_xor(acc.y, off);
        acc.z += __shfl_xor(acc.z, off);
        acc.w += __shfl_xor(acc.w, off);
        s     += __shfl_xor(s, off);
    }
    if (lane < 16) {
        float inv = (deg > 0) ? 1.f / s : 0.f;
        vf4 o = acc * inv;
        __builtin_nontemporal_store(o, &((vf4*)out)[(size_t)node * 16 + q]);
    }
}

// ---------------- round-1 scatter fallback (tiny ws) ----------------
__global__ void denom_kernel(const float* __restrict__ att,
                             const int* __restrict__ idx,
                             float* __restrict__ denom, int M) {
    int e = blockIdx.x * blockDim.x + threadIdx.x;
    if (e < M) atomicAdd(&denom[idx[e]], expf(att[e]));
}

__global__ void scatter_kernel(const float4* __restrict__ edges4,
                               const float* __restrict__ att,
                               const int* __restrict__ idx,
                               const float* __restrict__ denom,
                               float* __restrict__ out, int M) {
    long long tid = (long long)blockIdx.x * blockDim.x + threadIdx.x;
    int e = (int)(tid >> 4);
    if (e >= M) return;
    int q = (int)(tid & 15);
    int node = idx[e];
    float alpha = expf(att[e]) / denom[node];
    float4 v = edges4[(size_t)e * 16 + q];
    float* o = out + (size_t)node * F + q * 4;
    atomicAdd(o + 0, v.x * alpha);
    atomicAdd(o + 1, v.y * alpha);
    atomicAdd(o + 2, v.z * alpha);
    atomicAdd(o + 3, v.w * alpha);
}

extern "C" void kernel_launch(void* const* d_in, const int* in_sizes, int n_in,
                              void* d_out, int out_size, void* d_ws, size_t ws_size,
                              hipStream_t stream) {
    // inputs: 0=reference (unused, N*F), 1=edges (M*F), 2=attention (M), 3=edge_index (2*M)
    const float* edges = (const float*)d_in[1];
    const float* att   = (const float*)d_in[2];
    const int*   eidx  = (const int*)d_in[3];   // row 0 = receiver idx
    int M = in_sizes[2];
    int N = in_sizes[0] / F;
    float* out = (float*)d_out;

    int nb = (N + 255) / 256;
    int threads = 256;
    int blocksM = (M + threads - 1) / threads;

    // ws layout: [counts N][local_excl N][partials nb][pos M][pe 2M ints]
    size_t need = ((size_t)2 * N + nb + (size_t)3 * M) * sizeof(int);

    if (ws_size >= need) {
        int* counts     = (int*)d_ws;
        int* local_excl = counts + N;
        int* partials   = local_excl + N;
        int* pos        = partials + nb;
        int2* pe        = (int2*)(pos + M);

        int n4 = (N + 3) / 4;
        zero_kernel<<<(n4 + threads - 1) / threads, threads, 0, stream>>>((int4*)counts, n4);
        count_pos_kernel<<<blocksM, threads, 0, stream>>>(eidx, counts, pos, M);
        scanA_kernel<<<nb, 256, 0, stream>>>(counts, local_excl, partials, N);
        scanB_kernel<<<1, 64, 0, stream>>>(partials, nb);
        perm_kernel<<<blocksM, threads, 0, stream>>>(eidx, att, pos, local_excl,
                                                     partials, pe, M);
        int nodes_per_block = threads / 64;
        int blocksN = (N + nodes_per_block - 1) / nodes_per_block;
        gather_kernel<<<blocksN, threads, 0, stream>>>(
            (const vf4*)edges, pe, local_excl, partials, counts, out, N);
    } else {
        float* denom = (float*)d_ws;
        int nz = (N + 3) / 4;
        zero_kernel<<<(nz + threads - 1) / threads, threads, 0, stream>>>((int4*)denom, nz);
        int o4 = (out_size + 3) / 4;
        zero_kernel<<<(o4 + threads - 1) / threads, threads, 0, stream>>>((int4*)out, o4);
        denom_kernel<<<blocksM, threads, 0, stream>>>(att, eidx, denom, M);
        long long total = (long long)M * 16;
        long long blocks2 = (total + threads - 1) / threads;
        scatter_kernel<<<(int)blocks2, threads, 0, stream>>>(
            (const float4*)edges, att, eidx, denom, out, M);
    }
}

// Round 8
// 189.024 us; speedup vs baseline: 1.3730x; 1.0098x over previous
//
#include <hip/hip_runtime.h>

constexpr int F = 64;

typedef float vf4 __attribute__((ext_vector_type(4)));

// ---------------- zero scratch ----------------
__global__ void zero_kernel(int4* __restrict__ p, int n4) {
    int i = blockIdx.x * blockDim.x + threadIdx.x;
    if (i < n4) p[i] = make_int4(0, 0, 0, 0);
}

// ---------------- CSR build ----------------
// pass 1: count + record within-node position (removes pass-2 atomics)
__global__ void count_pos_kernel(const int* __restrict__ idx,
                                 int* __restrict__ counts,
                                 int* __restrict__ pos, int M) {
    int e = blockIdx.x * blockDim.x + threadIdx.x;
    if (e < M) pos[e] = atomicAdd(&counts[idx[e]], 1);
}

// per-block exclusive scan of 256 counts; block total -> partials[blockIdx]
__global__ void scanA_kernel(const int* __restrict__ counts,
                             int* __restrict__ local_excl,
                             int* __restrict__ partials, int N) {
    __shared__ int wsum[4];
    int i = blockIdx.x * 256 + threadIdx.x;
    int lane = threadIdx.x & 63, wid = threadIdx.x >> 6;
    int v = (i < N) ? counts[i] : 0;
    int incl = v;
    #pragma unroll
    for (int off = 1; off < 64; off <<= 1) {
        int n = __shfl_up(incl, off);
        if (lane >= off) incl += n;
    }
    if (lane == 63) wsum[wid] = incl;
    __syncthreads();
    if (threadIdx.x == 0) {
        int s = 0;
        #pragma unroll
        for (int w = 0; w < 4; ++w) { int t = wsum[w]; wsum[w] = s; s += t; }
        partials[blockIdx.x] = s;
    }
    __syncthreads();
    if (i < N) local_excl[i] = incl - v + wsum[wid];
}

// single-wave exclusive scan of block partials
__global__ void scanB_kernel(int* __restrict__ partials, int nb) {
    int lane = threadIdx.x;  // 64 threads
    int carry = 0;
    for (int base = 0; base < nb; base += 64) {
        int i = base + lane;
        int v = (i < nb) ? partials[i] : 0;
        int incl = v;
        #pragma unroll
        for (int off = 1; off < 64; off <<= 1) {
            int n = __shfl_up(incl, off);
            if (lane >= off) incl += n;
        }
        if (i < nb) partials[i] = incl - v + carry;
        carry += __shfl(incl, 63);
    }
}

// pass 2: atomic-free scatter of {edge_id, exp(att)} into CSR slots
__global__ void perm_kernel(const int* __restrict__ idx,
                            const float* __restrict__ att,
                            const int* __restrict__ pos,
                            const int* __restrict__ local_excl,
                            const int* __restrict__ partials,
                            int2* __restrict__ pe, int M) {
    int e = blockIdx.x * blockDim.x + threadIdx.x;
    if (e >= M) return;
    int node = idx[e];
    int slot = local_excl[node] + partials[node >> 8] + pos[e];
    pe[slot] = make_int2(e, __float_as_int(expf(att[e])));
}

// one wave per node. lane = (edge-slot lane>>4, feature-quad lane&15).
// Fully-unrolled 16-step load sequence per 64-slot chunk: all masked NT row
// loads issue before the accumulate chain consumes them (max per-wave MLP).
__global__ void gather_kernel(const vf4* __restrict__ edges4,
                              const int2* __restrict__ pe,
                              const int* __restrict__ local_excl,
                              const int* __restrict__ partials,
                              const int* __restrict__ counts,
                              float* __restrict__ out, int N) {
    int node = blockIdx.x * (blockDim.x >> 6) + (threadIdx.x >> 6);
    int lane = threadIdx.x & 63;
    if (node >= N) return;
    int base = local_excl[node] + partials[node >> 8];
    int deg  = counts[node];
    int grp = lane >> 4;   // which row-slot within each 4-row group
    int q   = lane & 15;   // feature quad
    vf4 acc = (vf4)(0.f);
    float s = 0.f;
    for (int c = 0; c < deg; c += 64) {
        int len = min(64, deg - c);
        int e = 0; float a = 0.f;
        if (lane < len) {
            int2 v = pe[base + c + lane];
            e = v.x; a = __int_as_float(v.y);
        }
        #pragma unroll
        for (int k = 0; k < 16; ++k) {
            int jj = k * 4 + grp;
            int ej   = __shfl(e, jj);
            float aj = __shfl(a, jj);
            if (jj < len) {   // masked: no wasted loads past the row tail
                vf4 v = __builtin_nontemporal_load(&edges4[(size_t)ej * 16 + q]);
                acc += aj * v;
                s += aj;
            }
        }
    }
    // combine the 4 lane-groups (xor 16, 32)
    #pragma unroll
    for (int off = 16; off < 64; off <<= 1) {
        acc.x += __shfl_xor(acc.x, off);
        acc.y += __shfl_xor(acc.y, off);
        acc.z += __shfl_xor(acc.z, off);
        acc.w += __shfl_xor(acc.w, off);
        s     += __shfl_xor(s, off);
    }
    if (lane < 16) {
        float inv = (deg > 0) ? 1.f / s : 0.f;
        vf4 o = acc * inv;
        __builtin_nontemporal_store(o, &((vf4*)out)[(size_t)node * 16 + q]);
    }
}

// ---------------- round-1 scatter fallback (tiny ws) ----------------
__global__ void denom_kernel(const float* __restrict__ att,
                             const int* __restrict__ idx,
                             float* __restrict__ denom, int M) {
    int e = blockIdx.x * blockDim.x + threadIdx.x;
    if (e < M) atomicAdd(&denom[idx[e]], expf(att[e]));
}

__global__ void scatter_kernel(const float4* __restrict__ edges4,
                               const float* __restrict__ att,
                               const int* __restrict__ idx,
                               const float* __restrict__ denom,
                               float* __restrict__ out, int M) {
    long long tid = (long long)blockIdx.x * blockDim.x + threadIdx.x;
    int e = (int)(tid >> 4);
    if (e >= M) return;
    int q = (int)(tid & 15);
    int node = idx[e];
    float alpha = expf(att[e]) / denom[node];
    float4 v = edges4[(size_t)e * 16 + q];
    float* o = out + (size_t)node * F + q * 4;
    atomicAdd(o + 0, v.x * alpha);
    atomicAdd(o + 1, v.y * alpha);
    atomicAdd(o + 2, v.z * alpha);
    atomicAdd(o + 3, v.w * alpha);
}

extern "C" void kernel_launch(void* const* d_in, const int* in_sizes, int n_in,
                              void* d_out, int out_size, void* d_ws, size_t ws_size,
                              hipStream_t stream) {
    // inputs: 0=reference (unused, N*F), 1=edges (M*F), 2=attention (M), 3=edge_index (2*M)
    const float* edges = (const float*)d_in[1];
    const float* att   = (const float*)d_in[2];
    const int*   eidx  = (const int*)d_in[3];   // row 0 = receiver idx
    int M = in_sizes[2];
    int N = in_sizes[0] / F;
    float* out = (float*)d_out;

    int nb = (N + 255) / 256;
    int threads = 256;
    int blocksM = (M + threads - 1) / threads;

    // ws layout: [counts N][local_excl N][partials nb][pos M][pe 2M ints]
    size_t need = ((size_t)2 * N + nb + (size_t)3 * M) * sizeof(int);

    if (ws_size >= need) {
        int* counts     = (int*)d_ws;
        int* local_excl = counts + N;
        int* partials   = local_excl + N;
        int* pos        = partials + nb;
        int2* pe        = (int2*)(pos + M);

        int n4 = (N + 3) / 4;
        zero_kernel<<<(n4 + threads - 1) / threads, threads, 0, stream>>>((int4*)counts, n4);
        count_pos_kernel<<<blocksM, threads, 0, stream>>>(eidx, counts, pos, M);
        scanA_kernel<<<nb, 256, 0, stream>>>(counts, local_excl, partials, N);
        scanB_kernel<<<1, 64, 0, stream>>>(partials, nb);
        perm_kernel<<<blocksM, threads, 0, stream>>>(eidx, att, pos, local_excl,
                                                     partials, pe, M);
        int nodes_per_block = threads / 64;
        int blocksN = (N + nodes_per_block - 1) / nodes_per_block;
        gather_kernel<<<blocksN, threads, 0, stream>>>(
            (const vf4*)edges, pe, local_excl, partials, counts, out, N);
    } else {
        float* denom = (float*)d_ws;
        int nz = (N + 3) / 4;
        zero_kernel<<<(nz + threads - 1) / threads, threads, 0, stream>>>((int4*)denom, nz);
        int o4 = (out_size + 3) / 4;
        zero_kernel<<<(o4 + threads - 1) / threads, threads, 0, stream>>>((int4*)out, o4);
        denom_kernel<<<blocksM, threads, 0, stream>>>(att, eidx, denom, M);
        long long total = (long long)M * 16;
        long long blocks2 = (total + threads - 1) / threads;
        scatter_kernel<<<(int)blocks2, threads, 0, stream>>>(
            (const float4*)edges, att, eidx, denom, out, M);
    }
}